// Round 5
// baseline (8420.922 us; speedup 1.0000x reference)
//
#include <hip/hip_runtime.h>
#include <stdint.h>

typedef unsigned short u16;
typedef unsigned int   u32;
typedef unsigned long long u64;

#define B_  64
#define T_  2048
#define I_  512
#define H_  512
#define G_  2048   // 4*H

typedef __attribute__((ext_vector_type(8))) __bf16 bf16x8;
typedef __attribute__((ext_vector_type(4))) float  f32x4;

// ---- workspace layout (bytes) ----
#define OFF_XB    0ull                         // x as bf16, [B][T][I]        128 MB
#define OFF_GX    134217728ull                 // gates_x bf16 [T][B][G]      512 MB
#define OFF_WXP   (OFF_GX + 536870912ull)      // Wx permuted bf16 [G][I]       2 MB
#define OFF_WHP   (OFF_WXP + 2097152ull)       // Wh permuted bf16 [G][H]       2 MB
#define OFF_BIAS  (OFF_WHP + 2097152ull)       // (bx+bh) permuted f32 [G]      8 KB
#define OFF_HBUF  (OFF_BIAS + 8192ull)         // tagged h, 2 x [64][256] u64 256 KB
#define WS_NEEDED (OFF_HBUF + 262144ull)

__device__ __forceinline__ float bf2f(u16 u) {
  union { float f; u32 u; } c; c.u = ((u32)u) << 16; return c.f;
}
__device__ __forceinline__ u16 f2bf(float f) {
  union { float f; u32 u; } c; c.f = f;
  u32 u = c.u;
  return (u16)((u + 0x7FFFu + ((u >> 16) & 1u)) >> 16);
}
__device__ __forceinline__ float sigmoidf_(float x) {
  return __fdividef(1.f, 1.f + __expf(-x));
}
__device__ __forceinline__ float tanhf_(float x) {
  return 1.f - __fdividef(2.f, 1.f + __expf(2.f * x));
}
__device__ __forceinline__ void async16(const u16* g, u16* l) {
  __builtin_amdgcn_global_load_lds((const __attribute__((address_space(1))) void*)g,
                                   (__attribute__((address_space(3))) void*)l,
                                   16, 0, 0);
}

// ---------------------------------------------------------------------------
// prep: permute+convert weights to bf16 (col order n = k*4 + gate), bias sum,
// zero BOTH tagged-h buffers (tag 0 == h_0 valid; ws re-poisoned every launch)
// ---------------------------------------------------------------------------
__global__ void __launch_bounds__(256)
prep_misc(const float* __restrict__ wx, const float* __restrict__ bx,
          const float* __restrict__ wh, const float* __restrict__ bh,
          u16* __restrict__ wxp, u16* __restrict__ whp,
          float* __restrict__ bias, u32* __restrict__ hbuf0)
{
  int idx = blockIdx.x * 256 + threadIdx.x;      // 0 .. 1048575
  int n = idx >> 9, k = idx & 511;
  long r = (long)(((n & 3) << 9) | (n >> 2)) * 512 + k;  // original row g*512+khid
  wxp[idx] = f2bf(wx[r]);
  whp[idx] = f2bf(wh[r]);
  if (idx < G_) {
    int rb = ((idx & 3) << 9) | (idx >> 2);
    bias[idx] = bx[rb] + bh[rb];
  }
  if (idx < 65536) hbuf0[idx] = 0u;              // zero 2 x 128KB tagged h
}

// ---------------------------------------------------------------------------
// convert x (fp32) -> bf16, same [B][T][I] layout
// ---------------------------------------------------------------------------
__global__ void __launch_bounds__(256)
conv_x(const float* __restrict__ x, u16* __restrict__ xb)
{
  long idx = ((long)blockIdx.x * 256 + threadIdx.x) * 4;
  float4 v = *(const float4*)(x + idx);
  u64 pk = (u64)f2bf(v.x) | ((u64)f2bf(v.y) << 16) |
           ((u64)f2bf(v.z) << 32) | ((u64)f2bf(v.w) << 48);
  *(u64*)(xb + idx) = pk;
}

// ---------------------------------------------------------------------------
// gates_x GEMM: gx[t][b][n] = sum_k x[b][t][k]*WxP[n][k] + biasP[n]
// (unchanged m97-structure 128x128 tile kernel)
// ---------------------------------------------------------------------------
__global__ void __launch_bounds__(256)
gemm_gates(const u16* __restrict__ xb, const u16* __restrict__ wxp,
           const float* __restrict__ bias, u16* __restrict__ gx)
{
  __shared__ __align__(16) u16 smem[16384];
  const int tid  = threadIdx.x;
  const int lane = tid & 63;
  const int w    = tid >> 6;
  const int tn   = blockIdx.x;
  const int tm   = blockIdx.y;
  const int wr   = w >> 1, wc = w & 1;

  const u16* gsrc[8];
  u16* ldst[8];
#pragma unroll
  for (int q = 0; q < 8; ++q) {
    int c   = w * 8 + q;
    int isB = c >= 16;
    int cc  = c & 15;
    int rloc = (cc >> 1) * 16 + (lane & 15);
    int koff = (cc & 1) * 32 + ((lane >> 4) << 3);
    if (!isB) {
      int m = tm * 128 + rloc;
      int bb = m & 63, tt = m >> 6;
      gsrc[q] = xb + (long)bb * (T_ * I_) + (long)tt * I_ + koff;
    } else {
      int n = tn * 128 + rloc;
      gsrc[q] = wxp + (long)n * I_ + koff;
    }
    ldst[q] = smem + isB * 8192 + cc * 512;
  }

  f32x4 acc[4][4] = {};
  for (int k0 = 0; k0 < I_; k0 += 64) {
#pragma unroll
    for (int q = 0; q < 8; ++q) async16(gsrc[q] + k0, ldst[q]);
    __syncthreads();
#pragma unroll
    for (int kb = 0; kb < 2; ++kb) {
      bf16x8 a[4], b[4];
#pragma unroll
      for (int i = 0; i < 4; ++i)
        a[i] = *(const bf16x8*)(smem + ((wr * 4 + i) * 2 + kb) * 512 + lane * 8);
#pragma unroll
      for (int j = 0; j < 4; ++j)
        b[j] = *(const bf16x8*)(smem + 8192 + ((wc * 4 + j) * 2 + kb) * 512 + lane * 8);
#pragma unroll
      for (int i = 0; i < 4; ++i)
#pragma unroll
        for (int j = 0; j < 4; ++j)
          acc[i][j] = __builtin_amdgcn_mfma_f32_16x16x32_bf16(a[i], b[j], acc[i][j], 0, 0, 0);
    }
    __syncthreads();
  }

#pragma unroll
  for (int j = 0; j < 4; ++j) {
    int n = tn * 128 + (wc * 4 + j) * 16 + (lane & 15);
    float bv = bias[n];
#pragma unroll
    for (int i = 0; i < 4; ++i) {
      int mbase = tm * 128 + (wr * 4 + i) * 16 + ((lane >> 4) << 2);
#pragma unroll
      for (int r = 0; r < 4; ++r) {
        int m = mbase + r;
        int tt = m >> 6, bb = m & 63;
        gx[(long)tt * (B_ * G_) + (long)bb * G_ + n] = f2bf(acc[i][j][r] + bv);
      }
    }
  }
}

// ---------------------------------------------------------------------------
// Recurrence v5 = round-2 protocol, 8-wave blocks (512 thr) so Wh is truly
// register-resident:
//  - wave owns 16 gate-cols -> 16 B-frags = 64 VGPR (fits; r2's 32 frags at
//    VGPR=104 were re-streamed from L2 every step, ~128KB/block/step)
//  - poll: 8 unconditional tagged loads per thread (branch-free, clustered)
//  - 1 cell per thread; pair-publish via __shfl_xor(h,1); even lanes store
//  - Hs double-buffered, ONE barrier per step (exact r2 protocol, no bypass)
//  - scr stride 36 f32 (16B-aligned, 2-way banks on scatter and read)
// ---------------------------------------------------------------------------
__global__ void __launch_bounds__(512, 2)
lstm_rec(const u16* __restrict__ gx, const u16* __restrict__ whp,
         u64* hbuf, float* __restrict__ out)
{
  __shared__ __align__(16) char lds[32768 + 18432];
  u16*  Hs  = (u16*)lds;                    // h tile, A-frag order, 2 x 16KB
  float* scr = (float*)(lds + 32768);       // per-wave gate scratch, 8 x 576 f32

  const int tid  = threadIdx.x;
  const int lane = tid & 63;
  const int w    = tid >> 6;                // 0..7
  const int bg   = blockIdx.x >> 4;         // 0..3  batch group (16 batches)
  const int kg   = blockIdx.x & 15;         // 0..15 k group (32 hidden cols)

  // preload this wave's 16 Wh B-fragments into registers (64 VGPR, resident)
  bf16x8 wfr[16];
  {
    const int n0   = kg * 128 + w * 16 + (lane & 15);
    const int koff = (lane >> 4) << 3;
#pragma unroll
    for (int kb = 0; kb < 16; ++kb)
      wfr[kb] = *(const bf16x8*)(whp + ((long)n0 << 9) + kb * 32 + koff);
  }

  // ---- staging constants: thread stages row (tid&15), word col (tid>>4)
  const int srow  = tid & 15;
  const int scol2 = tid >> 4;               // 0..31
  const u64* hsrc = hbuf + (long)(bg * 16 + srow) * 256 + scol2;
  // A-frag dest: word s*32+scol2 -> frag kb=2s+(scol2>>4), lane srow+(((scol2&15)>>2)<<4)
  u16* sdst = Hs + (scol2 >> 4) * 512 +
              (srow + (((scol2 & 15) >> 2) << 4)) * 8 + 2 * (scol2 & 3);

  // ---- cell-phase constants: lane owns cell (b16c, klocal)
  const int b16c   = lane >> 2;             // 0..15 batch within group
  const int klocal = lane & 3;              // 0..3 hidden col within wave
  const int kgl    = kg * 32 + w * 4 + klocal;  // global hidden col
  const int bglob  = bg * 16 + b16c;

  const u16* gxp0 = gx + (long)bglob * G_ + (long)kgl * 4;
  u64 gq = *(const u64*)gxp0;               // prefetch gx for t=0 (4 gates, 8B)

  u64* hdst = hbuf + (long)bglob * 256 + (kgl >> 1);
  float c0 = 0.f;                           // cell state in register

  for (int t = 0; t < T_; ++t) {
    const int par = t & 1;
    const u64* hp_ = hsrc + (size_t)par * 16384;

    // ---- poll tagged h_t (my 8 words) until every tag == t ----
    u64 v[8];
    for (;;) {
      bool ok = true;
#pragma unroll
      for (int s = 0; s < 8; ++s)
        v[s] = __hip_atomic_load(hp_ + s * 32, __ATOMIC_RELAXED, __HIP_MEMORY_SCOPE_AGENT);
#pragma unroll
      for (int s = 0; s < 8; ++s) ok &= ((u32)v[s] == (u32)t);
      if (ok) break;
      __builtin_amdgcn_s_sleep(1);
    }

    // ---- strip tags, stage into A-fragment-order LDS (buffer par) ----
    u16* sd = sdst + par * 8192;
#pragma unroll
    for (int s = 0; s < 8; ++s)
      *(u32*)(sd + s * 1024) = (u32)(v[s] >> 32);
    __syncthreads();                        // the only barrier per step

    // ---- gates(wave's 16 cols) = h_t @ Wh^T, 2 interleaved 8-chains ----
    const u16* Hb = Hs + par * 8192;
    f32x4 accP = {0.f,0.f,0.f,0.f}, accQ = {0.f,0.f,0.f,0.f};
#pragma unroll
    for (int kb = 0; kb < 16; kb += 2) {
      bf16x8 aA = *(const bf16x8*)(Hb + kb * 512 + lane * 8);
      bf16x8 aB = *(const bf16x8*)(Hb + (kb + 1) * 512 + lane * 8);
      accP = __builtin_amdgcn_mfma_f32_16x16x32_bf16(aA, wfr[kb],     accP, 0, 0, 0);
      accQ = __builtin_amdgcn_mfma_f32_16x16x32_bf16(aB, wfr[kb + 1], accQ, 0, 0, 0);
    }
    f32x4 acc = accP + accQ;

    // ---- scatter C frag to per-wave scratch [16 rows x stride 36] ----
    float* sw = scr + w * 576;
    {
      const int c  = lane & 15;
      const int bq = (lane >> 4) << 2;
#pragma unroll
      for (int r = 0; r < 4; ++r)
        sw[(bq + r) * 36 + c] = acc[r];
    }

    // ---- cell update (gq was prefetched a full step ago) ----
    u64 gqc = gq;
    if (t + 1 < T_) gq = *(const u64*)(gxp0 + (long)(t + 1) * (B_ * G_));

    const u16* gu = (const u16*)&gqc;
    f32x4 ga = *(const f32x4*)(sw + b16c * 36 + klocal * 4);

    float i0 = sigmoidf_(ga[0] + bf2f(gu[0]));
    float f0 = sigmoidf_(ga[1] + bf2f(gu[1]));
    float g0 = tanhf_   (ga[2] + bf2f(gu[2]));
    float o0 = sigmoidf_(ga[3] + bf2f(gu[3]));
    float cn = f0 * c0 + i0 * g0;
    float h  = o0 * tanhf_(cn);
    c0 = cn;

    // ---- pair up adjacent cols, publish h_{t+1} (tag rides with data) ----
    float hpart = __shfl_xor(h, 1);
    float cpart = __shfl_xor(cn, 1);
    if (!(lane & 1)) {
      u32 hp = ((u32)f2bf(hpart) << 16) | (u32)f2bf(h);
      u64 tv = ((u64)hp << 32) | (u32)(t + 1);
      __hip_atomic_store(hdst + (size_t)((t + 1) & 1) * 16384, tv,
                         __ATOMIC_RELAXED, __HIP_MEMORY_SCOPE_AGENT);
      float2 hv; hv.x = h; hv.y = hpart;
      *(float2*)(out + ((long)bglob * T_ + t) * H_ + kgl) = hv;   // output[b][t][k]
      if (t == T_ - 1) {
        float2 cv; cv.x = cn; cv.y = cpart;
        *(float2*)(out + (size_t)B_ * T_ * H_ + (long)bglob * H_ + kgl) = hv;            // h_n
        *(float2*)(out + (size_t)B_ * T_ * H_ + B_ * H_ + (long)bglob * H_ + kgl) = cv;  // c_n
      }
    }
    // no end-of-step barrier: Hs double-buffered; tag protocol + the single
    // stage->MFMA barrier order all cross-wave LDS accesses (r2 semantics).
  }
}

extern "C" void kernel_launch(void* const* d_in, const int* in_sizes, int n_in,
                              void* d_out, int out_size, void* d_ws, size_t ws_size,
                              hipStream_t stream)
{
  (void)in_sizes; (void)n_in; (void)out_size;
  if (ws_size < WS_NEEDED) return;   // need ~645 MB scratch

  const float* x  = (const float*)d_in[0];
  const float* Wx = (const float*)d_in[1];
  const float* bx = (const float*)d_in[2];
  const float* Wh = (const float*)d_in[3];
  const float* bh = (const float*)d_in[4];
  float* out = (float*)d_out;
  char* ws = (char*)d_ws;
  u16* xb     = (u16*)(ws + OFF_XB);
  u16* gx     = (u16*)(ws + OFF_GX);
  u16* wxp    = (u16*)(ws + OFF_WXP);
  u16* whp    = (u16*)(ws + OFF_WHP);
  float* bias = (float*)(ws + OFF_BIAS);
  u64* hbuf   = (u64*)(ws + OFF_HBUF);

  prep_misc<<<4096, 256, 0, stream>>>(Wx, bx, Wh, bh, wxp, whp, bias, (u32*)hbuf);
  conv_x<<<65536, 256, 0, stream>>>(x, xb);
  gemm_gates<<<dim3(16, 1024), 256, 0, stream>>>(xb, wxp, bias, gx);
  lstm_rec<<<64, 512, 0, stream>>>(gx, whp, hbuf, out);
}